// Round 1
// baseline (1349.645 us; speedup 1.0000x reference)
//
#include <hip/hip_runtime.h>
#include <math.h>

#define HID 64
#define INC 256
#define LN_EPS 1e-5f
#define ALPHA 0.1f

__device__ __forceinline__ float gelu_exact(float x) {
    return 0.5f * x * (1.0f + erff(x * 0.70710678118654752f));
}

__device__ __forceinline__ float wave_sum64(float v) {
#pragma unroll
    for (int m = 1; m < 64; m <<= 1) v += __shfl_xor(v, m, 64);
    return v;
}

// ---------------- GEMM1: h1 = gelu(x @ W1 + b1) ----------------
// 64 rows x 64 cols per block, 256 threads, 4x4 micro-tile, K tiled by 64.
__global__ __launch_bounds__(256) void k_gemm1(const float* __restrict__ x,
                                               const float* __restrict__ W1,
                                               const float* __restrict__ b1,
                                               float* __restrict__ out, int N) {
    __shared__ float xT[64][68];  // [k][row], padded
    __shared__ float Ws[64][64];  // [k][col]
    const int t = threadIdx.x;
    const int row0 = blockIdx.x * 64;
    const int rr = (t >> 4) << 2;  // 0..60
    const int cc = (t & 15) << 2;  // 0..60
    float acc[4][4] = {};

    for (int kt = 0; kt < 4; ++kt) {
        const int kb = kt * 64;
#pragma unroll
        for (int p0 = 0; p0 < 4; ++p0) {
            int p = p0 * 256 + t;
            int r = p >> 4;
            int c4 = (p & 15) << 2;
            int row = row0 + r;
            if (row > N - 1) row = N - 1;
            const float4 v = reinterpret_cast<const float4*>(x + (size_t)row * INC + kb + c4)[0];
            xT[c4 + 0][r] = v.x;
            xT[c4 + 1][r] = v.y;
            xT[c4 + 2][r] = v.z;
            xT[c4 + 3][r] = v.w;
        }
#pragma unroll
        for (int p0 = 0; p0 < 4; ++p0) {
            int p = p0 * 256 + t;
            int k = p >> 4;
            int c4 = (p & 15) << 2;
            const float4 w = reinterpret_cast<const float4*>(W1 + (size_t)(kb + k) * HID + c4)[0];
            reinterpret_cast<float4*>(&Ws[k][c4])[0] = w;
        }
        __syncthreads();
#pragma unroll 16
        for (int k = 0; k < 64; ++k) {
            const float4 xv = reinterpret_cast<float4*>(&xT[k][rr])[0];
            const float4 wv = reinterpret_cast<float4*>(&Ws[k][cc])[0];
            acc[0][0] += xv.x * wv.x; acc[0][1] += xv.x * wv.y; acc[0][2] += xv.x * wv.z; acc[0][3] += xv.x * wv.w;
            acc[1][0] += xv.y * wv.x; acc[1][1] += xv.y * wv.y; acc[1][2] += xv.y * wv.z; acc[1][3] += xv.y * wv.w;
            acc[2][0] += xv.z * wv.x; acc[2][1] += xv.z * wv.y; acc[2][2] += xv.z * wv.z; acc[2][3] += xv.z * wv.w;
            acc[3][0] += xv.w * wv.x; acc[3][1] += xv.w * wv.y; acc[3][2] += xv.w * wv.z; acc[3][3] += xv.w * wv.w;
        }
        __syncthreads();
    }

    const float4 bb = reinterpret_cast<const float4*>(b1 + cc)[0];
#pragma unroll
    for (int i = 0; i < 4; ++i) {
        int row = row0 + rr + i;
        if (row < N) {
            float4 o;
            o.x = gelu_exact(acc[i][0] + bb.x);
            o.y = gelu_exact(acc[i][1] + bb.y);
            o.z = gelu_exact(acc[i][2] + bb.z);
            o.w = gelu_exact(acc[i][3] + bb.w);
            reinterpret_cast<float4*>(out + (size_t)row * HID + cc)[0] = o;
        }
    }
}

// ---------------- LayerNorm (wave per row) ----------------
__global__ __launch_bounds__(256) void k_ln(const float* __restrict__ in,
                                            const float* __restrict__ g,
                                            const float* __restrict__ be,
                                            float* __restrict__ out, int N) {
    const int lane = threadIdx.x & 63;
    const int wid = threadIdx.x >> 6;
    const int row = blockIdx.x * 4 + wid;
    if (row >= N) return;
    float v = in[(size_t)row * HID + lane];
    float mu = wave_sum64(v) * (1.0f / 64.0f);
    float d = v - mu;
    float var = wave_sum64(d * d) * (1.0f / 64.0f);
    out[(size_t)row * HID + lane] = d * rsqrtf(var + LN_EPS) * g[lane] + be[lane];
}

// ---------------- degree count ----------------
__global__ __launch_bounds__(256) void k_count(const int* __restrict__ ei, int* __restrict__ cnt,
                                               int E) {
    int e = blockIdx.x * 256 + threadIdx.x;
    if (e < E) atomicAdd(&cnt[ei[E + e]], 1);
}

// ---------------- scan level A: per-1024-chunk exclusive scan + dinv ----------------
__global__ __launch_bounds__(256) void k_scanA(const int* __restrict__ cnt,
                                               int* __restrict__ rowstart,
                                               float* __restrict__ dinv,
                                               int* __restrict__ bsum, int N) {
    __shared__ int sums[256];
    const int t = threadIdx.x;
    const int base = blockIdx.x * 1024 + t * 4;
    int c0 = 0, c1 = 0, c2 = 0, c3 = 0;
    if (base + 3 < N) {
        const int4 c = reinterpret_cast<const int4*>(cnt + base)[0];
        c0 = c.x; c1 = c.y; c2 = c.z; c3 = c.w;
    } else {
        if (base + 0 < N) c0 = cnt[base + 0];
        if (base + 1 < N) c1 = cnt[base + 1];
        if (base + 2 < N) c2 = cnt[base + 2];
        if (base + 3 < N) c3 = cnt[base + 3];
    }
    const int tsum = c0 + c1 + c2 + c3;
    sums[t] = tsum;
    __syncthreads();
#pragma unroll
    for (int off = 1; off < 256; off <<= 1) {
        int add = (t >= off) ? sums[t - off] : 0;
        __syncthreads();
        sums[t] += add;
        __syncthreads();
    }
    const int ex = sums[t] - tsum;
    int pre0 = ex, pre1 = ex + c0, pre2 = ex + c0 + c1, pre3 = ex + c0 + c1 + c2;
    if (base + 0 < N) { rowstart[base + 0] = pre0; dinv[base + 0] = rsqrtf((float)(c0 + 1)); }
    if (base + 1 < N) { rowstart[base + 1] = pre1; dinv[base + 1] = rsqrtf((float)(c1 + 1)); }
    if (base + 2 < N) { rowstart[base + 2] = pre2; dinv[base + 2] = rsqrtf((float)(c2 + 1)); }
    if (base + 3 < N) { rowstart[base + 3] = pre3; dinv[base + 3] = rsqrtf((float)(c3 + 1)); }
    if (t == 255) bsum[blockIdx.x] = sums[255];
}

// ---------------- scan level B: exclusive scan of chunk sums (1 block) ----------------
__global__ __launch_bounds__(256) void k_scanB(const int* __restrict__ bsum, int* __restrict__ boff,
                                               int nchunks) {
    __shared__ int s[256];
    const int t = threadIdx.x;
    const int v = (t < nchunks) ? bsum[t] : 0;
    s[t] = v;
    __syncthreads();
#pragma unroll
    for (int off = 1; off < 256; off <<= 1) {
        int add = (t >= off) ? s[t - off] : 0;
        __syncthreads();
        s[t] += add;
        __syncthreads();
    }
    boff[t] = s[t] - v;
}

// ---------------- scan level C: add chunk offsets, init cursor ----------------
__global__ __launch_bounds__(256) void k_scanC(int* __restrict__ rowstart, const int* __restrict__ boff,
                                               int* __restrict__ cursor, int N, int E) {
    int i = blockIdx.x * 256 + threadIdx.x;
    if (i < N) {
        int rs = rowstart[i] + boff[i >> 10];
        rowstart[i] = rs;
        cursor[i] = rs;
    }
    if (i == 0) rowstart[N] = E;
}

// ---------------- fill CSR: (src, norm) per edge, bucketed by dst ----------------
__global__ __launch_bounds__(256) void k_fill(const int* __restrict__ ei,
                                              const float* __restrict__ dinv,
                                              int* __restrict__ cursor,
                                              int2* __restrict__ csr, int E) {
    int e = blockIdx.x * 256 + threadIdx.x;
    if (e >= E) return;
    const int row = ei[e];
    const int col = ei[E + e];
    const int p = atomicAdd(&cursor[col], 1);
    const float nrm = dinv[row] * dinv[col];
    csr[p] = make_int2(row, __float_as_int(nrm));
}

// ---------------- APPNP propagation step (wave per node) ----------------
__global__ __launch_bounds__(256) void k_prop(const float* __restrict__ hin,
                                              const float* __restrict__ h0,
                                              float* __restrict__ hout,
                                              const int2* __restrict__ csr,
                                              const int* __restrict__ rowstart,
                                              const float* __restrict__ dinv, int N) {
    const int lane = threadIdx.x & 63;
    const int wid = threadIdx.x >> 6;
    const int node = blockIdx.x * 4 + wid;
    if (node >= N) return;
    const float di = dinv[node];
    float acc = di * di * hin[(size_t)node * HID + lane];
    const int s = rowstart[node];
    const int e0 = rowstart[node + 1];
    int e = s;
    for (; e + 1 < e0; e += 2) {
        const int2 a = csr[e];
        const int2 b = csr[e + 1];
        const float ha = hin[(size_t)a.x * HID + lane];
        const float hb = hin[(size_t)b.x * HID + lane];
        acc += __int_as_float(a.y) * ha;
        acc += __int_as_float(b.y) * hb;
    }
    if (e < e0) {
        const int2 a = csr[e];
        acc += __int_as_float(a.y) * hin[(size_t)a.x * HID + lane];
    }
    hout[(size_t)node * HID + lane] =
        (1.0f - ALPHA) * acc + ALPHA * h0[(size_t)node * HID + lane];
}

// ---------------- final: out = LN(gelu(h)) @ W2 + b2 ----------------
__global__ __launch_bounds__(256) void k_final(const float* __restrict__ h,
                                               const float* __restrict__ g2,
                                               const float* __restrict__ be2,
                                               const float* __restrict__ W2,
                                               const float* __restrict__ b2,
                                               float* __restrict__ out, int N) {
    const int lane = threadIdx.x & 63;
    const int wid = threadIdx.x >> 6;
    const int gw = blockIdx.x * 4 + wid;
    const int nw = gridDim.x * 4;
    float w2r[64];
#pragma unroll
    for (int k = 0; k < 64; ++k) w2r[k] = W2[k * HID + lane];
    const float bb = b2[lane];
    const float gg = g2[lane];
    const float bt = be2[lane];
    for (int row = gw; row < N; row += nw) {
        float v = gelu_exact(h[(size_t)row * HID + lane]);
        const float mu = wave_sum64(v) * (1.0f / 64.0f);
        const float d = v - mu;
        const float var = wave_sum64(d * d) * (1.0f / 64.0f);
        const float vn = d * rsqrtf(var + LN_EPS) * gg + bt;
        float acc = bb;
#pragma unroll
        for (int k = 0; k < 64; ++k) acc += __shfl(vn, k, 64) * w2r[k];
        out[(size_t)row * HID + lane] = acc;
    }
}

extern "C" void kernel_launch(void* const* d_in, const int* in_sizes, int n_in,
                              void* d_out, int out_size, void* d_ws, size_t ws_size,
                              hipStream_t stream) {
    const float* x   = (const float*)d_in[0];
    const int*   ei  = (const int*)d_in[1];
    const float* W1  = (const float*)d_in[2];
    const float* b1  = (const float*)d_in[3];
    const float* g1  = (const float*)d_in[4];
    const float* be1 = (const float*)d_in[5];
    const float* g2  = (const float*)d_in[6];
    const float* be2 = (const float*)d_in[7];
    const float* W2  = (const float*)d_in[8];
    const float* b2  = (const float*)d_in[9];
    float* out = (float*)d_out;

    const int N = in_sizes[0] / INC;
    const int E = in_sizes[1] / 2;

    char* ws = (char*)d_ws;
    size_t o = 0;
    auto alloc = [&](size_t bytes) { size_t r = o; o += (bytes + 255) & ~(size_t)255; return r; };
    float* h1       = (float*)(ws + alloc((size_t)N * HID * 4));
    float* h2       = (float*)(ws + alloc((size_t)N * HID * 4));
    float* h0       = (float*)(ws + alloc((size_t)N * HID * 4));
    float* dinv     = (float*)(ws + alloc((size_t)N * 4));
    int*   cnt      = (int*)(ws + alloc((size_t)N * 4));
    int*   rowstart = (int*)(ws + alloc((size_t)(N + 1) * 4));
    int*   cursor   = (int*)(ws + alloc((size_t)N * 4));
    int*   boff     = (int*)(ws + alloc(1024));
    int*   bsum     = (int*)(ws + alloc(1024));
    int2*  csr      = (int2*)(ws + alloc((size_t)E * 8));

    const int nchunks = (N + 1023) / 1024;

    hipMemsetAsync(cnt, 0, (size_t)N * 4, stream);
    k_gemm1<<<(N + 63) / 64, 256, 0, stream>>>(x, W1, b1, h1, N);
    k_ln<<<(N + 3) / 4, 256, 0, stream>>>(h1, g1, be1, h0, N);
    k_count<<<(E + 255) / 256, 256, 0, stream>>>(ei, cnt, E);
    k_scanA<<<nchunks, 256, 0, stream>>>(cnt, rowstart, dinv, bsum, N);
    k_scanB<<<1, 256, 0, stream>>>(bsum, boff, nchunks);
    k_scanC<<<(N + 255) / 256, 256, 0, stream>>>(rowstart, boff, cursor, N, E);
    k_fill<<<(E + 255) / 256, 256, 0, stream>>>(ei, dinv, cursor, csr, E);

    float* bufs[2] = {h1, h2};
    const float* pin = h0;
    for (int k = 0; k < 10; ++k) {
        float* pout = bufs[k & 1];
        k_prop<<<(N + 3) / 4, 256, 0, stream>>>(pin, h0, pout, csr, rowstart, dinv, N);
        pin = pout;
    }
    // after 10 iters, pin == h2 (k=9 wrote bufs[1])
    k_final<<<1024, 256, 0, stream>>>(pin, g2, be2, W2, b2, out, N);
}

// Round 2
// 948.405 us; speedup vs baseline: 1.4231x; 1.4231x over previous
//
#include <hip/hip_runtime.h>
#include <math.h>

#define HID 64
#define INC 256
#define LN_EPS 1e-5f
#define ALPHA 0.1f

__device__ __forceinline__ float gelu_exact(float x) {
    return 0.5f * x * (1.0f + erff(x * 0.70710678118654752f));
}

__device__ __forceinline__ float wave_sum64(float v) {
#pragma unroll
    for (int m = 1; m < 64; m <<= 1) v += __shfl_xor(v, m, 64);
    return v;
}

__device__ __forceinline__ unsigned short f2bf(float f) {
    unsigned int u = __float_as_uint(f);
    unsigned int r = (u + 0x7fffu + ((u >> 16) & 1u)) >> 16;
    return (unsigned short)r;
}
__device__ __forceinline__ float bf_lo(unsigned int v) { return __uint_as_float(v << 16); }
__device__ __forceinline__ float bf_hi(unsigned int v) { return __uint_as_float(v & 0xffff0000u); }

// ---------------- GEMM1 + gelu + LN fused: h0 = LN(gelu(x @ W1 + b1)) (bf16 out) ---------
// 64 rows x 64 cols per block, 256 threads, 4x4 micro-tile, K tiled by 64.
__global__ __launch_bounds__(256) void k_gemm1ln(const float* __restrict__ x,
                                                 const float* __restrict__ W1,
                                                 const float* __restrict__ b1,
                                                 const float* __restrict__ g1,
                                                 const float* __restrict__ be1,
                                                 unsigned short* __restrict__ h0bf, int N) {
    __shared__ float xT[64][68];  // [k][row], padded; reused for gelu values [row][col]
    __shared__ float Ws[64][64];  // [k][col]
    const int t = threadIdx.x;
    const int row0 = blockIdx.x * 64;
    const int rr = (t >> 4) << 2;  // 0..60
    const int cc = (t & 15) << 2;  // 0..60
    float acc[4][4] = {};

    for (int kt = 0; kt < 4; ++kt) {
        const int kb = kt * 64;
#pragma unroll
        for (int p0 = 0; p0 < 4; ++p0) {
            int p = p0 * 256 + t;
            int r = p >> 4;
            int c4 = (p & 15) << 2;
            int row = row0 + r;
            if (row > N - 1) row = N - 1;
            const float4 v = reinterpret_cast<const float4*>(x + (size_t)row * INC + kb + c4)[0];
            xT[c4 + 0][r] = v.x;
            xT[c4 + 1][r] = v.y;
            xT[c4 + 2][r] = v.z;
            xT[c4 + 3][r] = v.w;
        }
#pragma unroll
        for (int p0 = 0; p0 < 4; ++p0) {
            int p = p0 * 256 + t;
            int k = p >> 4;
            int c4 = (p & 15) << 2;
            const float4 w = reinterpret_cast<const float4*>(W1 + (size_t)(kb + k) * HID + c4)[0];
            reinterpret_cast<float4*>(&Ws[k][c4])[0] = w;
        }
        __syncthreads();
#pragma unroll 16
        for (int k = 0; k < 64; ++k) {
            const float4 xv = reinterpret_cast<float4*>(&xT[k][rr])[0];
            const float4 wv = reinterpret_cast<float4*>(&Ws[k][cc])[0];
            acc[0][0] += xv.x * wv.x; acc[0][1] += xv.x * wv.y; acc[0][2] += xv.x * wv.z; acc[0][3] += xv.x * wv.w;
            acc[1][0] += xv.y * wv.x; acc[1][1] += xv.y * wv.y; acc[1][2] += xv.y * wv.z; acc[1][3] += xv.y * wv.w;
            acc[2][0] += xv.z * wv.x; acc[2][1] += xv.z * wv.y; acc[2][2] += xv.z * wv.z; acc[2][3] += xv.z * wv.w;
            acc[3][0] += xv.w * wv.x; acc[3][1] += xv.w * wv.y; acc[3][2] += xv.w * wv.z; acc[3][3] += xv.w * wv.w;
        }
        __syncthreads();
    }

    // epilogue: gelu -> LDS [row][col]
    const float4 bb = reinterpret_cast<const float4*>(b1 + cc)[0];
#pragma unroll
    for (int i = 0; i < 4; ++i) {
        xT[rr + i][cc + 0] = gelu_exact(acc[i][0] + bb.x);
        xT[rr + i][cc + 1] = gelu_exact(acc[i][1] + bb.y);
        xT[rr + i][cc + 2] = gelu_exact(acc[i][2] + bb.z);
        xT[rr + i][cc + 3] = gelu_exact(acc[i][3] + bb.w);
    }
    __syncthreads();

    // LayerNorm per row, wave per row (4 waves, 16 rows each), bf16 store
    const int lane = t & 63;
    const int w = t >> 6;
    const float gg = g1[lane];
    const float bt = be1[lane];
    for (int r = w; r < 64; r += 4) {
        const int row = row0 + r;
        if (row >= N) continue;  // uniform per wave
        float v = xT[r][lane];
        const float mu = wave_sum64(v) * (1.0f / 64.0f);
        const float d = v - mu;
        const float var = wave_sum64(d * d) * (1.0f / 64.0f);
        h0bf[(size_t)row * HID + lane] = f2bf(d * rsqrtf(var + LN_EPS) * gg + bt);
    }
}

// ---------------- degree count ----------------
__global__ __launch_bounds__(256) void k_count(const int* __restrict__ ei, int* __restrict__ cnt,
                                               int E) {
    int e = blockIdx.x * 256 + threadIdx.x;
    if (e < E) atomicAdd(&cnt[ei[E + e]], 1);
}

// ---------------- scan level A ----------------
__global__ __launch_bounds__(256) void k_scanA(const int* __restrict__ cnt,
                                               int* __restrict__ rowstart,
                                               float* __restrict__ dinv,
                                               int* __restrict__ bsum, int N) {
    __shared__ int sums[256];
    const int t = threadIdx.x;
    const int base = blockIdx.x * 1024 + t * 4;
    int c0 = 0, c1 = 0, c2 = 0, c3 = 0;
    if (base + 3 < N) {
        const int4 c = reinterpret_cast<const int4*>(cnt + base)[0];
        c0 = c.x; c1 = c.y; c2 = c.z; c3 = c.w;
    } else {
        if (base + 0 < N) c0 = cnt[base + 0];
        if (base + 1 < N) c1 = cnt[base + 1];
        if (base + 2 < N) c2 = cnt[base + 2];
        if (base + 3 < N) c3 = cnt[base + 3];
    }
    const int tsum = c0 + c1 + c2 + c3;
    sums[t] = tsum;
    __syncthreads();
#pragma unroll
    for (int off = 1; off < 256; off <<= 1) {
        int add = (t >= off) ? sums[t - off] : 0;
        __syncthreads();
        sums[t] += add;
        __syncthreads();
    }
    const int ex = sums[t] - tsum;
    int pre0 = ex, pre1 = ex + c0, pre2 = ex + c0 + c1, pre3 = ex + c0 + c1 + c2;
    if (base + 0 < N) { rowstart[base + 0] = pre0; dinv[base + 0] = rsqrtf((float)(c0 + 1)); }
    if (base + 1 < N) { rowstart[base + 1] = pre1; dinv[base + 1] = rsqrtf((float)(c1 + 1)); }
    if (base + 2 < N) { rowstart[base + 2] = pre2; dinv[base + 2] = rsqrtf((float)(c2 + 1)); }
    if (base + 3 < N) { rowstart[base + 3] = pre3; dinv[base + 3] = rsqrtf((float)(c3 + 1)); }
    if (t == 255) bsum[blockIdx.x] = sums[255];
}

// ---------------- scan level B ----------------
__global__ __launch_bounds__(256) void k_scanB(const int* __restrict__ bsum, int* __restrict__ boff,
                                               int nchunks) {
    __shared__ int s[256];
    const int t = threadIdx.x;
    const int v = (t < nchunks) ? bsum[t] : 0;
    s[t] = v;
    __syncthreads();
#pragma unroll
    for (int off = 1; off < 256; off <<= 1) {
        int add = (t >= off) ? s[t - off] : 0;
        __syncthreads();
        s[t] += add;
        __syncthreads();
    }
    boff[t] = s[t] - v;
}

// ---------------- scan level C ----------------
__global__ __launch_bounds__(256) void k_scanC(int* __restrict__ rowstart, const int* __restrict__ boff,
                                               int* __restrict__ cursor, int N, int E) {
    int i = blockIdx.x * 256 + threadIdx.x;
    if (i < N) {
        int rs = rowstart[i] + boff[i >> 10];
        rowstart[i] = rs;
        cursor[i] = rs;
    }
    if (i == 0) rowstart[N] = E;
}

// ---------------- fill CSR ----------------
__global__ __launch_bounds__(256) void k_fill(const int* __restrict__ ei,
                                              const float* __restrict__ dinv,
                                              int* __restrict__ cursor,
                                              int2* __restrict__ csr, int E) {
    int e = blockIdx.x * 256 + threadIdx.x;
    if (e >= E) return;
    const int row = ei[e];
    const int col = ei[E + e];
    const int p = atomicAdd(&cursor[col], 1);
    const float nrm = dinv[row] * dinv[col];
    csr[p] = make_int2(row, __float_as_int(nrm));
}

// ---------------- APPNP propagation step (wave per node, bf16 h) ----------------
// half-wave per edge: lane&31 = feature pair, 2 edge-pairs (4 edges) in flight.
__global__ __launch_bounds__(256) void k_prop(const unsigned short* __restrict__ hin,
                                              const unsigned short* __restrict__ h0,
                                              unsigned short* __restrict__ hout,
                                              const int2* __restrict__ csr,
                                              const int* __restrict__ rowstart,
                                              const float* __restrict__ dinv, int N) {
    const int lane = threadIdx.x & 63;
    const int half = lane >> 5;
    const int fl = lane & 31;
    const int node = blockIdx.x * 4 + (threadIdx.x >> 6);
    if (node >= N) return;
    const unsigned int* hin2 = (const unsigned int*)hin;
    const int s = rowstart[node];
    const int e0 = rowstart[node + 1];
    float ax = 0.0f, ay = 0.0f;
    for (int e = s; e < e0; e += 4) {
        const int i1 = e + half;
        const int i2 = e + 2 + half;
        const bool a1 = i1 < e0;
        const bool a2 = i2 < e0;
        const int2 c1 = csr[a1 ? i1 : s];
        const int2 c2 = csr[a2 ? i2 : s];
        const float n1 = a1 ? __int_as_float(c1.y) : 0.0f;
        const float n2 = a2 ? __int_as_float(c2.y) : 0.0f;
        const unsigned int v1 = hin2[(size_t)c1.x * 32 + fl];
        const unsigned int v2 = hin2[(size_t)c2.x * 32 + fl];
        ax += n1 * bf_lo(v1);
        ay += n1 * bf_hi(v1);
        ax += n2 * bf_lo(v2);
        ay += n2 * bf_hi(v2);
    }
    ax += __shfl_xor(ax, 32, 64);
    ay += __shfl_xor(ay, 32, 64);
    if (half == 0) {
        const float di = dinv[node];
        const float dd = di * di;
        const unsigned int sv = hin2[(size_t)node * 32 + fl];
        const unsigned int hv = ((const unsigned int*)h0)[(size_t)node * 32 + fl];
        const float rx = (1.0f - ALPHA) * (ax + dd * bf_lo(sv)) + ALPHA * bf_lo(hv);
        const float ry = (1.0f - ALPHA) * (ay + dd * bf_hi(sv)) + ALPHA * bf_hi(hv);
        ((unsigned int*)hout)[(size_t)node * 32 + fl] =
            (unsigned int)f2bf(rx) | ((unsigned int)f2bf(ry) << 16);
    }
}

// ---------------- final: out = LN(gelu(h)) @ W2 + b2 (bf16 in, f32 out) -------------
__global__ __launch_bounds__(256) void k_final(const unsigned short* __restrict__ h,
                                               const float* __restrict__ g2,
                                               const float* __restrict__ be2,
                                               const float* __restrict__ W2,
                                               const float* __restrict__ b2,
                                               float* __restrict__ out, int N) {
    const int lane = threadIdx.x & 63;
    const int wid = threadIdx.x >> 6;
    const int gw = blockIdx.x * 4 + wid;
    const int nw = gridDim.x * 4;
    float w2r[64];
#pragma unroll
    for (int k = 0; k < 64; ++k) w2r[k] = W2[k * HID + lane];
    const float bb = b2[lane];
    const float gg = g2[lane];
    const float bt = be2[lane];
    for (int row = gw; row < N; row += nw) {
        float v = gelu_exact(__uint_as_float((unsigned int)h[(size_t)row * HID + lane] << 16));
        const float mu = wave_sum64(v) * (1.0f / 64.0f);
        const float d = v - mu;
        const float var = wave_sum64(d * d) * (1.0f / 64.0f);
        const float vn = d * rsqrtf(var + LN_EPS) * gg + bt;
        float acc = bb;
#pragma unroll
        for (int k = 0; k < 64; ++k) acc += __shfl(vn, k, 64) * w2r[k];
        out[(size_t)row * HID + lane] = acc;
    }
}

extern "C" void kernel_launch(void* const* d_in, const int* in_sizes, int n_in,
                              void* d_out, int out_size, void* d_ws, size_t ws_size,
                              hipStream_t stream) {
    const float* x   = (const float*)d_in[0];
    const int*   ei  = (const int*)d_in[1];
    const float* W1  = (const float*)d_in[2];
    const float* b1  = (const float*)d_in[3];
    const float* g1  = (const float*)d_in[4];
    const float* be1 = (const float*)d_in[5];
    const float* g2  = (const float*)d_in[6];
    const float* be2 = (const float*)d_in[7];
    const float* W2  = (const float*)d_in[8];
    const float* b2  = (const float*)d_in[9];
    float* out = (float*)d_out;

    const int N = in_sizes[0] / INC;
    const int E = in_sizes[1] / 2;

    char* ws = (char*)d_ws;
    size_t o = 0;
    auto alloc = [&](size_t bytes) { size_t r = o; o += (bytes + 255) & ~(size_t)255; return r; };
    unsigned short* h0bf = (unsigned short*)(ws + alloc((size_t)N * HID * 2));
    unsigned short* ha   = (unsigned short*)(ws + alloc((size_t)N * HID * 2));
    unsigned short* hb   = (unsigned short*)(ws + alloc((size_t)N * HID * 2));
    float* dinv     = (float*)(ws + alloc((size_t)N * 4));
    int*   cnt      = (int*)(ws + alloc((size_t)N * 4));
    int*   rowstart = (int*)(ws + alloc((size_t)(N + 1) * 4));
    int*   cursor   = (int*)(ws + alloc((size_t)N * 4));
    int*   boff     = (int*)(ws + alloc(1024));
    int*   bsum     = (int*)(ws + alloc(1024));
    int2*  csr      = (int2*)(ws + alloc((size_t)E * 8));

    const int nchunks = (N + 1023) / 1024;

    hipMemsetAsync(cnt, 0, (size_t)N * 4, stream);
    k_gemm1ln<<<(N + 63) / 64, 256, 0, stream>>>(x, W1, b1, g1, be1, h0bf, N);
    k_count<<<(E + 255) / 256, 256, 0, stream>>>(ei, cnt, E);
    k_scanA<<<nchunks, 256, 0, stream>>>(cnt, rowstart, dinv, bsum, N);
    k_scanB<<<1, 256, 0, stream>>>(bsum, boff, nchunks);
    k_scanC<<<(N + 255) / 256, 256, 0, stream>>>(rowstart, boff, cursor, N, E);
    k_fill<<<(E + 255) / 256, 256, 0, stream>>>(ei, dinv, cursor, csr, E);

    unsigned short* bufs[2] = {ha, hb};
    const unsigned short* pin = h0bf;
    for (int k = 0; k < 10; ++k) {
        unsigned short* pout = bufs[k & 1];
        k_prop<<<(N + 3) / 4, 256, 0, stream>>>(pin, h0bf, pout, csr, rowstart, dinv, N);
        pin = pout;
    }
    k_final<<<1024, 256, 0, stream>>>(pin, g2, be2, W2, b2, out, N);
}

// Round 3
// 804.460 us; speedup vs baseline: 1.6777x; 1.1789x over previous
//
#include <hip/hip_runtime.h>
#include <math.h>

#define HID 64
#define INC 256
#define LN_EPS 1e-5f
#define ALPHA 0.1f

typedef unsigned short ushort_t;
typedef unsigned int uint_t;
using short8v = __attribute__((ext_vector_type(8))) short;
using float4v = __attribute__((ext_vector_type(4))) float;

__device__ __forceinline__ float gelu_exact(float x) {
    return 0.5f * x * (1.0f + erff(x * 0.70710678118654752f));
}

__device__ __forceinline__ float wave_sum64(float v) {
#pragma unroll
    for (int m = 1; m < 64; m <<= 1) v += __shfl_xor(v, m, 64);
    return v;
}

__device__ __forceinline__ ushort_t f2bf(float f) {
    uint_t u = __float_as_uint(f);
    return (ushort_t)((u + 0x7fffu + ((u >> 16) & 1u)) >> 16);
}
__device__ __forceinline__ float bf_lo(uint_t v) { return __uint_as_float(v << 16); }
__device__ __forceinline__ float bf_hi(uint_t v) { return __uint_as_float(v & 0xffff0000u); }

__device__ __forceinline__ void split_bf(float f, ushort_t& hi, ushort_t& lo) {
    uint_t ub = __float_as_uint(f);
    uint_t h = (ub + 0x7fffu + ((ub >> 16) & 1u)) >> 16;
    hi = (ushort_t)h;
    float fl = f - __uint_as_float(h << 16);
    uint_t lb = __float_as_uint(fl);
    lo = (ushort_t)((lb + 0x7fffu + ((lb >> 16) & 1u)) >> 16);
}

// ---------- prep: W1 [256][64] f32 -> swizzled W^T bf16 hi/lo [64][256] ----------
// element (col,k) stored at col*256 + ((k>>3)^(col&7))*8 + (k&7)
__global__ __launch_bounds__(256) void k_prepW(const float* __restrict__ W1,
                                               ushort_t* __restrict__ whi,
                                               ushort_t* __restrict__ wlo) {
    int e = blockIdx.x * 256 + threadIdx.x;  // 16384 total
    int col = e & 63, k = e >> 6;
    float f = W1[(size_t)k * HID + col];
    ushort_t hi, lo;
    split_bf(f, hi, lo);
    int idx = col * 256 + (((k >> 3) ^ (col & 7)) << 3) + (k & 7);
    whi[idx] = hi;
    wlo[idx] = lo;
}

// ---------- GEMM1 (MFMA) + gelu + LN fused: u0 = dinv * LN(gelu(x @ W1 + b1)) ----------
// block = 256 thr = 4 waves; wave -> 16 rows x 64 cols; K=256 in 8 steps of 32.
__global__ __launch_bounds__(256) void k_gemm1ln(const float* __restrict__ x,
                                                 const ushort_t* __restrict__ whi,
                                                 const ushort_t* __restrict__ wlo,
                                                 const float* __restrict__ b1,
                                                 const float* __restrict__ g1,
                                                 const float* __restrict__ be1,
                                                 const float* __restrict__ dinv,
                                                 ushort_t* __restrict__ u0, int N) {
    __shared__ ushort_t Wh[16384];
    __shared__ ushort_t Wl[16384];
    const int t = threadIdx.x;
    {
        const uint4* s1 = (const uint4*)whi;
        uint4* d1 = (uint4*)Wh;
        for (int i = t; i < 2048; i += 256) d1[i] = s1[i];
        const uint4* s2 = (const uint4*)wlo;
        uint4* d2 = (uint4*)Wl;
        for (int i = t; i < 2048; i += 256) d2[i] = s2[i];
    }
    __syncthreads();

    const int lane = t & 63, w = t >> 6;
    const int l15 = lane & 15, lg = lane >> 4;
    const int row0 = blockIdx.x * 64 + w * 16;
    int rowc = row0 + l15;
    if (rowc > N - 1) rowc = N - 1;
    const float* xr = x + (size_t)rowc * INC + lg * 8;

    float4 A0 = *(const float4*)(xr);
    float4 A1 = *(const float4*)(xr + 4);
    float4v acc[4];
#pragma unroll
    for (int i = 0; i < 4; ++i) acc[i] = (float4v){0.f, 0.f, 0.f, 0.f};

    union U8 { short8v v; ushort_t u[8]; };

#pragma unroll
    for (int t8 = 0; t8 < 8; ++t8) {
        float4 P0, P1;
        if (t8 < 7) {
            P0 = *(const float4*)(xr + (t8 + 1) * 32);
            P1 = *(const float4*)(xr + (t8 + 1) * 32 + 4);
        }
        U8 ahi, alo;
        {
            const float af[8] = {A0.x, A0.y, A0.z, A0.w, A1.x, A1.y, A1.z, A1.w};
#pragma unroll
            for (int j = 0; j < 8; ++j) split_bf(af[j], ahi.u[j], alo.u[j]);
        }
#pragma unroll
        for (int ct = 0; ct < 4; ++ct) {
            const int col = ct * 16 + l15;
            const int kb = t8 * 4 + lg;
            const int idx = col * 256 + ((kb ^ (col & 7)) << 3);
            short8v bhi = *(const short8v*)&Wh[idx];
            short8v blo = *(const short8v*)&Wl[idx];
            acc[ct] = __builtin_amdgcn_mfma_f32_16x16x32_bf16(ahi.v, bhi, acc[ct], 0, 0, 0);
            acc[ct] = __builtin_amdgcn_mfma_f32_16x16x32_bf16(ahi.v, blo, acc[ct], 0, 0, 0);
            acc[ct] = __builtin_amdgcn_mfma_f32_16x16x32_bf16(alo.v, bhi, acc[ct], 0, 0, 0);
        }
        if (t8 < 7) { A0 = P0; A1 = P1; }
    }

    // epilogue: bias + gelu + LN (row spread over 16 lanes x 4 col-tiles) + u0 = dinv*ln
    float b1c[4], g1c[4], bec[4];
#pragma unroll
    for (int ct = 0; ct < 4; ++ct) {
        const int col = ct * 16 + l15;
        b1c[ct] = b1[col];
        g1c[ct] = g1[col];
        bec[ct] = be1[col];
    }
    float gv[4][4];  // [ct][r]
#pragma unroll
    for (int ct = 0; ct < 4; ++ct)
#pragma unroll
        for (int r = 0; r < 4; ++r) gv[ct][r] = gelu_exact(acc[ct][r] + b1c[ct]);

    float mu[4], rsv[4];
#pragma unroll
    for (int r = 0; r < 4; ++r) {
        float p = gv[0][r] + gv[1][r] + gv[2][r] + gv[3][r];
        p += __shfl_xor(p, 1, 64);
        p += __shfl_xor(p, 2, 64);
        p += __shfl_xor(p, 4, 64);
        p += __shfl_xor(p, 8, 64);
        mu[r] = p * (1.0f / 64.0f);
        float d0 = gv[0][r] - mu[r], d1 = gv[1][r] - mu[r];
        float d2 = gv[2][r] - mu[r], d3 = gv[3][r] - mu[r];
        float p2 = d0 * d0 + d1 * d1 + d2 * d2 + d3 * d3;
        p2 += __shfl_xor(p2, 1, 64);
        p2 += __shfl_xor(p2, 2, 64);
        p2 += __shfl_xor(p2, 4, 64);
        p2 += __shfl_xor(p2, 8, 64);
        rsv[r] = rsqrtf(p2 * (1.0f / 64.0f) + LN_EPS);
    }
#pragma unroll
    for (int r = 0; r < 4; ++r) {
        const int row = row0 + lg * 4 + r;
        if (row < N) {
            const float di = dinv[row];
#pragma unroll
            for (int ct = 0; ct < 4; ++ct) {
                const float ln = (gv[ct][r] - mu[r]) * rsv[r] * g1c[ct] + bec[ct];
                u0[(size_t)row * HID + ct * 16 + l15] = f2bf(di * ln);
            }
        }
    }
}

// ---------------- degree count ----------------
__global__ __launch_bounds__(256) void k_count(const int* __restrict__ ei, int* __restrict__ cnt,
                                               int E) {
    int e = blockIdx.x * 256 + threadIdx.x;
    if (e < E) atomicAdd(&cnt[ei[E + e]], 1);
}

// ---------------- scan level A ----------------
__global__ __launch_bounds__(256) void k_scanA(const int* __restrict__ cnt,
                                               int* __restrict__ rowstart,
                                               float* __restrict__ dinv,
                                               int* __restrict__ bsum, int N) {
    __shared__ int sums[256];
    const int t = threadIdx.x;
    const int base = blockIdx.x * 1024 + t * 4;
    int c0 = 0, c1 = 0, c2 = 0, c3 = 0;
    if (base + 3 < N) {
        const int4 c = reinterpret_cast<const int4*>(cnt + base)[0];
        c0 = c.x; c1 = c.y; c2 = c.z; c3 = c.w;
    } else {
        if (base + 0 < N) c0 = cnt[base + 0];
        if (base + 1 < N) c1 = cnt[base + 1];
        if (base + 2 < N) c2 = cnt[base + 2];
        if (base + 3 < N) c3 = cnt[base + 3];
    }
    const int tsum = c0 + c1 + c2 + c3;
    sums[t] = tsum;
    __syncthreads();
#pragma unroll
    for (int off = 1; off < 256; off <<= 1) {
        int add = (t >= off) ? sums[t - off] : 0;
        __syncthreads();
        sums[t] += add;
        __syncthreads();
    }
    const int ex = sums[t] - tsum;
    int pre0 = ex, pre1 = ex + c0, pre2 = ex + c0 + c1, pre3 = ex + c0 + c1 + c2;
    if (base + 0 < N) { rowstart[base + 0] = pre0; dinv[base + 0] = rsqrtf((float)(c0 + 1)); }
    if (base + 1 < N) { rowstart[base + 1] = pre1; dinv[base + 1] = rsqrtf((float)(c1 + 1)); }
    if (base + 2 < N) { rowstart[base + 2] = pre2; dinv[base + 2] = rsqrtf((float)(c2 + 1)); }
    if (base + 3 < N) { rowstart[base + 3] = pre3; dinv[base + 3] = rsqrtf((float)(c3 + 1)); }
    if (t == 255) bsum[blockIdx.x] = sums[255];
}

// ---------------- scan level B ----------------
__global__ __launch_bounds__(256) void k_scanB(const int* __restrict__ bsum, int* __restrict__ boff,
                                               int nchunks) {
    __shared__ int s[256];
    const int t = threadIdx.x;
    const int v = (t < nchunks) ? bsum[t] : 0;
    s[t] = v;
    __syncthreads();
#pragma unroll
    for (int off = 1; off < 256; off <<= 1) {
        int add = (t >= off) ? s[t - off] : 0;
        __syncthreads();
        s[t] += add;
        __syncthreads();
    }
    boff[t] = s[t] - v;
}

// ---------------- scan level C ----------------
__global__ __launch_bounds__(256) void k_scanC(int* __restrict__ rowstart, const int* __restrict__ boff,
                                               int* __restrict__ cursor, int N, int E) {
    int i = blockIdx.x * 256 + threadIdx.x;
    if (i < N) {
        int rs = rowstart[i] + boff[i >> 10];
        rowstart[i] = rs;
        cursor[i] = rs;
    }
    if (i == 0) rowstart[N] = E;
}

// ---------------- fill CSR (src only; u-space needs no per-edge weight) ----------------
__global__ __launch_bounds__(256) void k_fill(const int* __restrict__ ei,
                                              int* __restrict__ cursor,
                                              int* __restrict__ csr, int E) {
    int e = blockIdx.x * 256 + threadIdx.x;
    if (e >= E) return;
    const int row = ei[e];
    const int col = ei[E + e];
    const int p = atomicAdd(&cursor[col], 1);
    csr[p] = row;
}

// ---------------- APPNP step in u-space: u' = (1-a)*dinv^2*(sum_adj u + u[d]) + a*u0 ----
// wave per node; quarter-wave (16 lanes) per edge, uint2 (4 bf16) per lane; 8 edges/iter.
__global__ __launch_bounds__(256) void k_prop(const ushort_t* __restrict__ uin,
                                              const ushort_t* __restrict__ u0,
                                              ushort_t* __restrict__ uout,
                                              const int* __restrict__ csr,
                                              const int* __restrict__ rowstart,
                                              const float* __restrict__ dinv, int N) {
    const int t = threadIdx.x;
    const int lane = t & 63;
    const int q = lane >> 4, fl = lane & 15;
    const int node = blockIdx.x * 4 + (t >> 6);
    if (node >= N) return;
    const uint2* U = (const uint2*)uin;
    const int s = rowstart[node];
    const int e0 = rowstart[node + 1];
    float a0 = 0.f, a1 = 0.f, a2 = 0.f, a3 = 0.f;
    for (int e = s; e < e0; e += 8) {
        const int i1 = e + q;
        const int i2 = e + 4 + q;
        const bool ok1 = i1 < e0;
        const bool ok2 = i2 < e0;
        const int s1 = csr[ok1 ? i1 : s];
        const int s2 = csr[ok2 ? i2 : s];
        const uint2 v1 = U[(size_t)s1 * 16 + fl];
        const uint2 v2 = U[(size_t)s2 * 16 + fl];
        const float f1 = ok1 ? 1.0f : 0.0f;
        const float f2 = ok2 ? 1.0f : 0.0f;
        a0 = fmaf(f1, bf_lo(v1.x), a0);
        a1 = fmaf(f1, bf_hi(v1.x), a1);
        a2 = fmaf(f1, bf_lo(v1.y), a2);
        a3 = fmaf(f1, bf_hi(v1.y), a3);
        a0 = fmaf(f2, bf_lo(v2.x), a0);
        a1 = fmaf(f2, bf_hi(v2.x), a1);
        a2 = fmaf(f2, bf_lo(v2.y), a2);
        a3 = fmaf(f2, bf_hi(v2.y), a3);
    }
    a0 += __shfl_xor(a0, 16, 64); a0 += __shfl_xor(a0, 32, 64);
    a1 += __shfl_xor(a1, 16, 64); a1 += __shfl_xor(a1, 32, 64);
    a2 += __shfl_xor(a2, 16, 64); a2 += __shfl_xor(a2, 32, 64);
    a3 += __shfl_xor(a3, 16, 64); a3 += __shfl_xor(a3, 32, 64);
    if (lane < 16) {
        const uint2 ud = U[(size_t)node * 16 + fl];
        const uint2 uz = ((const uint2*)u0)[(size_t)node * 16 + fl];
        const float di = dinv[node];
        const float c = (1.0f - ALPHA) * di * di;
        const float r0 = c * (a0 + bf_lo(ud.x)) + ALPHA * bf_lo(uz.x);
        const float r1 = c * (a1 + bf_hi(ud.x)) + ALPHA * bf_hi(uz.x);
        const float r2 = c * (a2 + bf_lo(ud.y)) + ALPHA * bf_lo(uz.y);
        const float r3 = c * (a3 + bf_hi(ud.y)) + ALPHA * bf_hi(uz.y);
        uint2 o;
        o.x = (uint_t)f2bf(r0) | ((uint_t)f2bf(r1) << 16);
        o.y = (uint_t)f2bf(r2) | ((uint_t)f2bf(r3) << 16);
        ((uint2*)uout)[(size_t)node * 16 + fl] = o;
    }
}

// ---------------- final: out = LN(gelu(u/dinv)) @ W2 + b2 ----------------
__global__ __launch_bounds__(256) void k_final(const ushort_t* __restrict__ u,
                                               const int* __restrict__ cnt,
                                               const float* __restrict__ g2,
                                               const float* __restrict__ be2,
                                               const float* __restrict__ W2,
                                               const float* __restrict__ b2,
                                               float* __restrict__ out, int N) {
    const int lane = threadIdx.x & 63;
    const int wid = threadIdx.x >> 6;
    const int gw = blockIdx.x * 4 + wid;
    const int nw = gridDim.x * 4;
    float w2r[64];
#pragma unroll
    for (int k = 0; k < 64; ++k) w2r[k] = W2[k * HID + lane];
    const float bb = b2[lane];
    const float gg = g2[lane];
    const float bt = be2[lane];
    for (int row = gw; row < N; row += nw) {
        const float sc = sqrtf((float)(cnt[row] + 1));  // 1/dinv
        float v = gelu_exact(__uint_as_float((uint_t)u[(size_t)row * HID + lane] << 16) * sc);
        const float mu = wave_sum64(v) * (1.0f / 64.0f);
        const float d = v - mu;
        const float var = wave_sum64(d * d) * (1.0f / 64.0f);
        const float vn = d * rsqrtf(var + LN_EPS) * gg + bt;
        float acc = bb;
#pragma unroll
        for (int k = 0; k < 64; ++k) acc += __shfl(vn, k, 64) * w2r[k];
        out[(size_t)row * HID + lane] = acc;
    }
}

extern "C" void kernel_launch(void* const* d_in, const int* in_sizes, int n_in,
                              void* d_out, int out_size, void* d_ws, size_t ws_size,
                              hipStream_t stream) {
    const float* x   = (const float*)d_in[0];
    const int*   ei  = (const int*)d_in[1];
    const float* W1  = (const float*)d_in[2];
    const float* b1  = (const float*)d_in[3];
    const float* g1  = (const float*)d_in[4];
    const float* be1 = (const float*)d_in[5];
    const float* g2  = (const float*)d_in[6];
    const float* be2 = (const float*)d_in[7];
    const float* W2  = (const float*)d_in[8];
    const float* b2  = (const float*)d_in[9];
    float* out = (float*)d_out;

    const int N = in_sizes[0] / INC;
    const int E = in_sizes[1] / 2;

    char* ws = (char*)d_ws;
    size_t o = 0;
    auto alloc = [&](size_t bytes) { size_t r = o; o += (bytes + 255) & ~(size_t)255; return r; };
    ushort_t* u0 = (ushort_t*)(ws + alloc((size_t)N * HID * 2));
    ushort_t* ua = (ushort_t*)(ws + alloc((size_t)N * HID * 2));
    ushort_t* ub = (ushort_t*)(ws + alloc((size_t)N * HID * 2));
    float* dinv     = (float*)(ws + alloc((size_t)N * 4));
    int*   cnt      = (int*)(ws + alloc((size_t)N * 4));
    int*   rowstart = (int*)(ws + alloc((size_t)(N + 1) * 4));
    int*   cursor   = (int*)(ws + alloc((size_t)N * 4));
    int*   boff     = (int*)(ws + alloc(1024));
    int*   bsum     = (int*)(ws + alloc(1024));
    ushort_t* whi   = (ushort_t*)(ws + alloc(16384 * 2));
    ushort_t* wlo   = (ushort_t*)(ws + alloc(16384 * 2));
    int*   csr      = (int*)(ws + alloc((size_t)E * 4));

    const int nchunks = (N + 1023) / 1024;

    hipMemsetAsync(cnt, 0, (size_t)N * 4, stream);
    k_prepW<<<64, 256, 0, stream>>>(W1, whi, wlo);
    k_count<<<(E + 255) / 256, 256, 0, stream>>>(ei, cnt, E);
    k_scanA<<<nchunks, 256, 0, stream>>>(cnt, rowstart, dinv, bsum, N);
    k_scanB<<<1, 256, 0, stream>>>(bsum, boff, nchunks);
    k_scanC<<<(N + 255) / 256, 256, 0, stream>>>(rowstart, boff, cursor, N, E);
    k_fill<<<(E + 255) / 256, 256, 0, stream>>>(ei, cursor, csr, E);
    k_gemm1ln<<<(N + 63) / 64, 256, 0, stream>>>(x, whi, wlo, b1, g1, be1, dinv, u0, N);

    ushort_t* bufs[2] = {ua, ub};
    const ushort_t* pin = u0;
    for (int k = 0; k < 10; ++k) {
        ushort_t* pout = bufs[k & 1];
        k_prop<<<(N + 3) / 4, 256, 0, stream>>>(pin, u0, pout, csr, rowstart, dinv, N);
        pin = pout;
    }
    k_final<<<1024, 256, 0, stream>>>(pin, cnt, g2, be2, W2, b2, out, N);
}